// Round 10
// baseline (271.449 us; speedup 1.0000x reference)
//
#include <hip/hip_runtime.h>
#include <hip/hip_bf16.h>

// Problem constants
#define B_    2
#define QN    100
#define NP    6
#define WS2   49
#define CC    256
#define NHH   8
#define HDD   32
#define NWIN  600            // Q*Np windows per batch
#define O_PER_B 7526400      // NH*WS2*NWIN*HD

// ws layout (bytes): xT fp32 | wbp bf16 frag-packed [48][8][64][8] | O fp32
#define XT_BYTES   8388608
#define WB_BYTES   393216

#define SPB_LD 264   // bf16 sp row stride (shorts)
#define QK_LD  520   // QK/P region row stride (shorts); 260 dwords = 4 mod 32 (proven family)
#define VT_OFF 25480 // shorts; QK region = 49*520 = 25480 (spb 64*264=16896 unioned under it)
#define VT_LD  50    // Vt row stride (shorts); 25 dwords, gcd(25,32)=1 -> conflict-free scatter
#define LDS_SHORTS (VT_OFF + 256 * VT_LD + 64)   // + tail pad

typedef __attribute__((ext_vector_type(8))) short bf16x8;
typedef __attribute__((ext_vector_type(4))) float f32x4;

__device__ __forceinline__ unsigned short f2bf(float f) {
  union { float f; unsigned int i; } v; v.f = f;
  unsigned int x = v.i;
  x += 0x7fffu + ((x >> 16) & 1u);   // round-to-nearest-even
  return (unsigned short)(x >> 16);
}

// ---------- K0: x (B,C,H,W) -> xT (B,H*W,C) ----------
__global__ void k0_transpose(const float* __restrict__ x, float* __restrict__ xT) {
  __shared__ float tile[32][33];
  int b  = blockIdx.z;
  int hw0 = blockIdx.x * 32;
  int c0  = blockIdx.y * 32;
  const float* src = x + (size_t)b * CC * 4096;
  float* dst = xT + (size_t)b * 4096 * CC;
  #pragma unroll
  for (int i = threadIdx.y; i < 32; i += 8)
    tile[i][threadIdx.x] = src[(size_t)(c0 + i) * 4096 + hw0 + threadIdx.x];
  __syncthreads();
  #pragma unroll
  for (int i = threadIdx.y; i < 32; i += 8)
    dst[(size_t)(hw0 + i) * CC + c0 + threadIdx.x] = tile[threadIdx.x][i];
}

// ---------- K05: w_qkv fp32 -> bf16, repacked into MFMA B-fragment order ----------
__global__ void k05_wpack(const float* __restrict__ w_qkv, unsigned short* __restrict__ wbp) {
  int g = blockIdx.x * 256 + threadIdx.x;       // 0..24575
  int lane = g & 63;
  int ks = (g >> 6) & 7;
  int nt = g >> 9;                              // 0..47
  int n  = nt * 16 + (lane & 15);
  int k0 = ks * 32 + (lane >> 4) * 8;
  const float* src = w_qkv + (size_t)n * CC + k0;
  float4 lo = *(const float4*)(src);
  float4 hi = *(const float4*)(src + 4);
  unsigned short o[8] = { f2bf(lo.x), f2bf(lo.y), f2bf(lo.z), f2bf(lo.w),
                          f2bf(hi.x), f2bf(hi.y), f2bf(hi.z), f2bf(hi.w) };
  *(uint4*)(wbp + (size_t)g * 8) = *(uint4*)o;
}

// ---------- K1: FUSED sample + QKV GEMM + attention (qkv never leaves LDS) ----------
// Wave wv computes QKV cols [wv*64,+64) of Q,K,V = exactly heads {2wv,2wv+1}.
// After the afrag barrier every wave is independent: GEMM -> LDS -> attention
// -> O store, zero further barriers. Eliminates the 88MB qkv write + 90MB read.
__launch_bounds__(256, 2)
__global__ void k1_fused(const float* __restrict__ xT,
                         const float* __restrict__ polys,
                         const unsigned short* __restrict__ wbp,
                         const float* __restrict__ b_qkv,
                         float* __restrict__ o_ws) {
  __shared__ __align__(16) unsigned short lds[LDS_SHORTS];
  __shared__ float co_x0[WS2], co_y0[WS2], co_wx[WS2], co_wy[WS2];
  unsigned short* spb = lds;                    // [64][SPB_LD], rows 49..63 zeroed
  const int tid = threadIdx.x;
  const int m = blockIdx.x;
  const int b = blockIdx.y;

  // Phase A: coords (grid scramble: n = m*49+r)
  if (tid < WS2) {
    int n = m * WS2 + tid;
    int q = n / (WS2 * NP);
    int p = (n / NP) % WS2;
    int a = n % NP;
    const float* pc = polys + (size_t)(b * QN + q) * 12;
    float al = (float)a * 0.2f;
    float py = pc[0];
    float px = pc[6];
    #pragma unroll
    for (int i = 1; i < 6; i++) { py = py * al + pc[i]; px = px * al + pc[6 + i]; }
    py = 2.0f * py - 1.0f;
    px = 2.0f * px - 1.0f;
    float gy = py + (2.0f * (-4.0f + (float)(p / 7) * (7.0f / 6.0f))) * (1.0f / 64.0f);
    float gx = px + (2.0f * (-4.0f + (float)(p % 7) * (7.0f / 6.0f))) * (1.0f / 64.0f);
    // NOTE the reference swap: fx from grid_y, fy from grid_x
    float fx = (gy + 1.0f) * 0.5f * 63.0f;
    float fy = (gx + 1.0f) * 0.5f * 63.0f;
    float x0 = floorf(fx), y0 = floorf(fy);
    co_x0[tid] = x0; co_y0[tid] = y0;
    co_wx[tid] = fx - x0; co_wy[tid] = fy - y0;
  }
  // zero spb pad rows 49..63
  {
    unsigned int* z = (unsigned int*)(spb + WS2 * SPB_LD);
    for (int i = tid; i < 15 * SPB_LD / 2; i += 256) z[i] = 0u;
  }
  // zero Vt col-49 slot of each row + tail pad (guards NaN bit-patterns; PV
  // reads k=49..63 hit these / next-row data, multiplied by exact-zero P)
  lds[VT_OFF + tid * VT_LD + 49] = 0;
  if (tid < 64) lds[VT_OFF + 256 * VT_LD + tid] = 0;
  __syncthreads();

  // Phase B: bilinear sampling, thread = channel, depth-1 pipeline
  const float* xb = xT + (size_t)b * (4096 * CC);
  float n00, n01, n10, n11, wxn, wyn;
  {
    float x0 = co_x0[0], y0 = co_y0[0];
    wxn = co_wx[0]; wyn = co_wy[0];
    float x1 = x0 + 1.0f, y1 = y0 + 1.0f;
    int xi0 = (int)fminf(fmaxf(x0, 0.0f), 63.0f);
    int yi0 = (int)fminf(fmaxf(y0, 0.0f), 63.0f);
    int xi1 = (int)fminf(fmaxf(x1, 0.0f), 63.0f);
    int yi1 = (int)fminf(fmaxf(y1, 0.0f), 63.0f);
    bool vx0 = (x0 >= 0.0f) && (x0 <= 63.0f);
    bool vx1 = (x1 >= 0.0f) && (x1 <= 63.0f);
    bool vy0 = (y0 >= 0.0f) && (y0 <= 63.0f);
    bool vy1 = (y1 >= 0.0f) && (y1 <= 63.0f);
    n00 = (vx0 && vy0) ? xb[(yi0 * 64 + xi0) * CC + tid] : 0.0f;
    n01 = (vx1 && vy0) ? xb[(yi0 * 64 + xi1) * CC + tid] : 0.0f;
    n10 = (vx0 && vy1) ? xb[(yi1 * 64 + xi0) * CC + tid] : 0.0f;
    n11 = (vx1 && vy1) ? xb[(yi1 * 64 + xi1) * CC + tid] : 0.0f;
  }
  for (int r = 0; r < WS2; r++) {
    float c00 = n00, c01 = n01, c10 = n10, c11 = n11;
    float wx = wxn, wy = wyn;
    if (r + 1 < WS2) {
      int rn = r + 1;
      float x0 = co_x0[rn], y0 = co_y0[rn];
      wxn = co_wx[rn]; wyn = co_wy[rn];
      float x1 = x0 + 1.0f, y1 = y0 + 1.0f;
      int xi0 = (int)fminf(fmaxf(x0, 0.0f), 63.0f);
      int yi0 = (int)fminf(fmaxf(y0, 0.0f), 63.0f);
      int xi1 = (int)fminf(fmaxf(x1, 0.0f), 63.0f);
      int yi1 = (int)fminf(fmaxf(y1, 0.0f), 63.0f);
      bool vx0 = (x0 >= 0.0f) && (x0 <= 63.0f);
      bool vx1 = (x1 >= 0.0f) && (x1 <= 63.0f);
      bool vy0 = (y0 >= 0.0f) && (y0 <= 63.0f);
      bool vy1 = (y1 >= 0.0f) && (y1 <= 63.0f);
      n00 = (vx0 && vy0) ? xb[(yi0 * 64 + xi0) * CC + tid] : 0.0f;
      n01 = (vx1 && vy0) ? xb[(yi0 * 64 + xi1) * CC + tid] : 0.0f;
      n10 = (vx0 && vy1) ? xb[(yi1 * 64 + xi0) * CC + tid] : 0.0f;
      n11 = (vx1 && vy1) ? xb[(yi1 * 64 + xi1) * CC + tid] : 0.0f;
    }
    float s = c00 * (1.0f - wy) * (1.0f - wx) + c01 * (1.0f - wy) * wx
            + c10 * wy * (1.0f - wx) + c11 * wy * wx;
    spb[r * SPB_LD + tid] = f2bf(s);
  }
  __syncthreads();

  const int lane = tid & 63;
  const int wv = tid >> 6;
  const int lm = lane & 15;
  const int lg = lane >> 4;

  // A-fragments into registers (held; spb region is repurposed below)
  bf16x8 afrag[4][8];
  #pragma unroll
  for (int mt = 0; mt < 4; mt++)
    #pragma unroll
    for (int ks = 0; ks < 8; ks++)
      afrag[mt][ks] = *(const bf16x8*)(spb + (mt * 16 + lm) * SPB_LD + ks * 32 + lg * 8);
  __syncthreads();   // spb dead everywhere -> region becomes QK/P storage

  // GEMM: 3 chunks of 4 N-tiles. jc0: Q cols [wv*64,+64); jc1: K; jc2: V->Vt.
  #pragma unroll
  for (int jc = 0; jc < 3; jc++) {
    const int nt0 = (jc == 0) ? 4 * wv : (jc == 1) ? 16 + 4 * wv : 32 + 4 * wv;
    f32x4 acc[4][4];
    #pragma unroll
    for (int j4 = 0; j4 < 4; j4++) {
      float bias = b_qkv[(nt0 + j4) * 16 + lm];
      #pragma unroll
      for (int mt = 0; mt < 4; mt++) acc[mt][j4] = (f32x4){bias, bias, bias, bias};
    }
    #pragma unroll
    for (int ks = 0; ks < 8; ks++) {
      #pragma unroll
      for (int j4 = 0; j4 < 4; j4++) {
        bf16x8 bfrag = *(const bf16x8*)(wbp + (size_t)(((nt0 + j4) * 8 + ks) * 64 + lane) * 8);
        #pragma unroll
        for (int mt = 0; mt < 4; mt++)
          acc[mt][j4] = __builtin_amdgcn_mfma_f32_16x16x32_bf16(afrag[mt][ks], bfrag, acc[mt][j4], 0, 0, 0);
      }
    }
    if (jc < 2) {
      // Q/K -> QK region [r][col=j], 16-short contiguous per store (2-way max)
      #pragma unroll
      for (int mt = 0; mt < 4; mt++)
        #pragma unroll
        for (int reg = 0; reg < 4; reg++) {
          int r = mt * 16 + lg * 4 + reg;
          if (r < WS2) {
            #pragma unroll
            for (int j4 = 0; j4 < 4; j4++)
              lds[r * QK_LD + (nt0 + j4) * 16 + lm] = f2bf(acc[mt][j4][reg]);
          }
        }
    } else {
      // V -> Vt transposed: Vt[vcol][r], vcol = (nt0-32+j4)*16+lm
      #pragma unroll
      for (int mt = 0; mt < 4; mt++)
        #pragma unroll
        for (int reg = 0; reg < 4; reg++) {
          int r = mt * 16 + lg * 4 + reg;
          if (r < WS2) {
            #pragma unroll
            for (int j4 = 0; j4 < 4; j4++) {
              int vcol = (4 * wv + j4) * 16 + lm;
              lds[VT_OFF + vcol * VT_LD + r] = f2bf(acc[mt][j4][reg]);
            }
          }
        }
    }
  }
  // no barrier: each wave reads only its own Q/K/V columns below

  const float scale = 0.17677669529663687f;  // 1/sqrt(32)
  // preload Q,K frags for BOTH heads (P store clobbers the Q strip)
  bf16x8 qf[2][4], kf[2][4];
  #pragma unroll
  for (int hh = 0; hh < 2; hh++) {
    int h = 2 * wv + hh;
    #pragma unroll
    for (int mt = 0; mt < 4; mt++) {
      int r = mt * 16 + lm; if (r > 48) r = 48;
      qf[hh][mt] = *(const bf16x8*)(lds + r * QK_LD + h * HDD + lg * 8);
      kf[hh][mt] = *(const bf16x8*)(lds + r * QK_LD + 256 + h * HDD + lg * 8);
    }
  }

  for (int hh = 0; hh < 2; hh++) {
    const int h = 2 * wv + hh;
    // S = Q K^T (C-layout: col r2 = nt*16+lm, row p = mt*16+lg*4+reg)
    f32x4 s[4][4];
    #pragma unroll
    for (int mt = 0; mt < 4; mt++)
      #pragma unroll
      for (int nt = 0; nt < 4; nt++) {
        s[mt][nt] = (f32x4){0.f, 0.f, 0.f, 0.f};
        s[mt][nt] = __builtin_amdgcn_mfma_f32_16x16x32_bf16(qf[hh][mt], kf[hh][nt], s[mt][nt], 0, 0, 0);
      }
    #pragma unroll
    for (int mt = 0; mt < 4; mt++)
      #pragma unroll
      for (int nt = 0; nt < 4; nt++) {
        bool badcol = (nt == 3) && (lm > 0);
        #pragma unroll
        for (int reg = 0; reg < 4; reg++)
          s[mt][nt][reg] = badcol ? -1e30f : s[mt][nt][reg] * scale;
      }
    // softmax over keys (pos_bias cancels exactly)
    #pragma unroll
    for (int mt = 0; mt < 4; mt++) {
      #pragma unroll
      for (int reg = 0; reg < 4; reg++) {
        float mx = fmaxf(fmaxf(s[mt][0][reg], s[mt][1][reg]),
                         fmaxf(s[mt][2][reg], s[mt][3][reg]));
        #pragma unroll
        for (int off = 1; off < 16; off <<= 1) mx = fmaxf(mx, __shfl_xor(mx, off));
        float sum = 0.0f;
        #pragma unroll
        for (int nt = 0; nt < 4; nt++) {
          float e = __expf(s[mt][nt][reg] - mx);
          s[mt][nt][reg] = e;
          sum += e;
        }
        #pragma unroll
        for (int off = 1; off < 16; off <<= 1) sum += __shfl_xor(sum, off);
        float inv = 1.0f / sum;
        #pragma unroll
        for (int nt = 0; nt < 4; nt++) s[mt][nt][reg] *= inv;
      }
    }
    // P (bf16) -> dead Q strip [p][wv*64 + r2]; cols 49..63 are exact zeros
    #pragma unroll
    for (int mt = 0; mt < 4; mt++)
      #pragma unroll
      for (int nt = 0; nt < 4; nt++)
        #pragma unroll
        for (int reg = 0; reg < 4; reg++) {
          int p = mt * 16 + lg * 4 + reg;
          if (p < WS2) lds[p * QK_LD + wv * 64 + nt * 16 + lm] = f2bf(s[mt][nt][reg]);
        }
    // O = P V
    f32x4 o[4][2];
    #pragma unroll
    for (int mt = 0; mt < 4; mt++)
      #pragma unroll
      for (int nt2 = 0; nt2 < 2; nt2++) o[mt][nt2] = (f32x4){0.f, 0.f, 0.f, 0.f};
    #pragma unroll
    for (int ks = 0; ks < 2; ks++) {
      bf16x8 vf[2];
      #pragma unroll
      for (int nt2 = 0; nt2 < 2; nt2++)
        vf[nt2] = *(const bf16x8*)(lds + VT_OFF + (h * HDD + nt2 * 16 + lm) * VT_LD + ks * 32 + lg * 8);
      #pragma unroll
      for (int mt = 0; mt < 4; mt++) {
        bf16x8 af = *(const bf16x8*)(lds + (mt * 16 + lm) * QK_LD + wv * 64 + ks * 32 + lg * 8);
        #pragma unroll
        for (int nt2 = 0; nt2 < 2; nt2++)
          o[mt][nt2] = __builtin_amdgcn_mfma_f32_16x16x32_bf16(af, vf[nt2], o[mt][nt2], 0, 0, 0);
      }
    }
    // store O: o_ws[b][((h*49+p)*600+m)*32+d]
    float* ob = o_ws + (size_t)b * O_PER_B + ((size_t)h * WS2 * NWIN + m) * HDD;
    #pragma unroll
    for (int mt = 0; mt < 4; mt++)
      #pragma unroll
      for (int reg = 0; reg < 4; reg++) {
        int p = mt * 16 + lg * 4 + reg;
        if (p < WS2) {
          #pragma unroll
          for (int nt2 = 0; nt2 < 2; nt2++)
            ob[(size_t)p * (NWIN * HDD) + nt2 * 16 + lm] = o[mt][nt2][reg];
        }
      }
  }
}

// ---------- K3: conv (49-tap over p') + projection ----------
__global__ void k3_conv_proj(const float* __restrict__ o_ws,
                             const float* __restrict__ conv_w,
                             const float* __restrict__ conv_b,
                             const float* __restrict__ w_proj,
                             const float* __restrict__ b_proj,
                             float* __restrict__ out) {
  __shared__ float yv[CC];
  __shared__ float cw[WS2];
  const int tid = threadIdx.x;
  const int np = blockIdx.x;
  const int b = blockIdx.y;
  if (tid < WS2) cw[tid] = conv_w[tid];
  __syncthreads();
  const float* base = o_ws + (size_t)b * O_PER_B + (size_t)np * (WS2 * CC);
  float acc = conv_b[0];
  for (int p = 0; p < WS2; p++)
    acc += cw[p] * base[p * CC + tid];
  yv[tid] = acc;
  __syncthreads();
  const float4* y4 = (const float4*)yv;
  const float4* w4 = (const float4*)(w_proj + (size_t)tid * CC);
  float s = b_proj[tid];
  float s2 = 0.0f;
  #pragma unroll 8
  for (int c4 = 0; c4 < 64; c4++) {
    float4 a = y4[c4], wv2 = w4[c4];
    s2 += a.x * wv2.x + a.y * wv2.y + a.z * wv2.z + a.w * wv2.w;
  }
  out[((size_t)(b * NWIN + np)) * CC + tid] = s + s2;
}

extern "C" void kernel_launch(void* const* d_in, const int* in_sizes, int n_in,
                              void* d_out, int out_size, void* d_ws, size_t ws_size,
                              hipStream_t stream) {
  const float* x        = (const float*)d_in[0];
  const float* polys    = (const float*)d_in[1];
  const float* w_qkv    = (const float*)d_in[2];
  const float* b_qkv    = (const float*)d_in[3];
  const float* w_proj   = (const float*)d_in[4];
  const float* b_proj   = (const float*)d_in[5];
  const float* conv_w   = (const float*)d_in[6];
  const float* conv_b   = (const float*)d_in[7];
  float* out = (float*)d_out;

  char* ws = (char*)d_ws;
  float* xT = (float*)ws;
  unsigned short* wbp = (unsigned short*)(ws + XT_BYTES);
  float* o_ws = (float*)(ws + XT_BYTES + WB_BYTES);

  hipLaunchKernelGGL(k0_transpose, dim3(128, 8, 2), dim3(32, 8), 0, stream, x, xT);
  hipLaunchKernelGGL(k05_wpack, dim3(96), dim3(256), 0, stream, w_qkv, wbp);
  hipLaunchKernelGGL(k1_fused, dim3(NWIN, B_), dim3(256), 0, stream,
                     xT, polys, wbp, b_qkv, o_ws);
  hipLaunchKernelGGL(k3_conv_proj, dim3(NWIN, B_), dim3(256), 0, stream,
                     o_ws, conv_w, conv_b, w_proj, b_proj, out);
}

// Round 11
// 225.195 us; speedup vs baseline: 1.2054x; 1.2054x over previous
//
#include <hip/hip_runtime.h>
#include <hip/hip_bf16.h>

// Problem constants
#define B_    2
#define QN    100
#define NP    6
#define WS2   49
#define CC    256
#define NHH   8
#define HDD   32
#define NWIN  600            // Q*Np windows per batch
#define O_PER_B 7526400      // NH*WS2*NWIN*HD

// ws layout (bytes): xT fp32 | wbp bf16 frag-packed [48][8][64][8] | qkv bf16 [1200][49][768] | O fp32
#define XT_BYTES   8388608
#define WB_BYTES   393216
#define QKV_SHORTS_PER_WIN (WS2 * 768)      // 37632 shorts
#define QKV_BYTES  (1200 * WS2 * 768 * 2)   // 90316800

#define SPB_LD 264   // bf16 sp row stride (shorts)
#define CW_LD  72    // per-wave C line-assembly row stride (144B rows, 16B-aligned)

typedef __attribute__((ext_vector_type(8))) short bf16x8;
typedef __attribute__((ext_vector_type(4))) float f32x4;

__device__ __forceinline__ unsigned short f2bf(float f) {
  union { float f; unsigned int i; } v; v.f = f;
  unsigned int x = v.i;
  x += 0x7fffu + ((x >> 16) & 1u);   // round-to-nearest-even
  return (unsigned short)(x >> 16);
}

// ---------- K0: x (B,C,H,W) -> xT (B,H*W,C) ----------
__global__ void k0_transpose(const float* __restrict__ x, float* __restrict__ xT) {
  __shared__ float tile[32][33];
  int b  = blockIdx.z;
  int hw0 = blockIdx.x * 32;
  int c0  = blockIdx.y * 32;
  const float* src = x + (size_t)b * CC * 4096;
  float* dst = xT + (size_t)b * 4096 * CC;
  #pragma unroll
  for (int i = threadIdx.y; i < 32; i += 8)
    tile[i][threadIdx.x] = src[(size_t)(c0 + i) * 4096 + hw0 + threadIdx.x];
  __syncthreads();
  #pragma unroll
  for (int i = threadIdx.y; i < 32; i += 8)
    dst[(size_t)(hw0 + i) * CC + c0 + threadIdx.x] = tile[threadIdx.x][i];
}

// ---------- K05: w_qkv fp32 -> bf16, repacked into MFMA B-fragment order ----------
__global__ void k05_wpack(const float* __restrict__ w_qkv, unsigned short* __restrict__ wbp) {
  int g = blockIdx.x * 256 + threadIdx.x;       // 0..24575
  int lane = g & 63;
  int ks = (g >> 6) & 7;
  int nt = g >> 9;                              // 0..47
  int n  = nt * 16 + (lane & 15);
  int k0 = ks * 32 + (lane >> 4) * 8;
  const float* src = w_qkv + (size_t)n * CC + k0;
  float4 lo = *(const float4*)(src);
  float4 hi = *(const float4*)(src + 4);
  unsigned short o[8] = { f2bf(lo.x), f2bf(lo.y), f2bf(lo.z), f2bf(lo.w),
                          f2bf(hi.x), f2bf(hi.y), f2bf(hi.z), f2bf(hi.w) };
  *(uint4*)(wbp + (size_t)g * 8) = *(uint4*)o;
}

// ---------- K1: per-window sample + MFMA QKV GEMM -> qkv_ws (bf16, [win][r][j]) ----------
// (r9 structure, proven 69us: 16-row Cw assembly, full-line stores, depth-1
// sampling pipeline, register double-buffered bfrag.)
__launch_bounds__(256, 3)
__global__ void k1_sample_qkv(const float* __restrict__ xT,
                              const float* __restrict__ polys,
                              const unsigned short* __restrict__ wbp,
                              const float* __restrict__ b_qkv,
                              unsigned short* __restrict__ qkv_ws) {
  __shared__ __align__(16) unsigned short spb[64 * SPB_LD];   // rows 49..63 zeroed
  __shared__ __align__(16) unsigned short Cwbuf[4][16 * CW_LD];
  __shared__ float co_x0[WS2], co_y0[WS2], co_wx[WS2], co_wy[WS2];
  const int tid = threadIdx.x;
  const int m = blockIdx.x;
  const int b = blockIdx.y;

  // Phase A: coords for the 49 rows of this window (grid scramble: n = m*49+r)
  if (tid < WS2) {
    int n = m * WS2 + tid;
    int q = n / (WS2 * NP);
    int p = (n / NP) % WS2;
    int a = n % NP;
    const float* pc = polys + (size_t)(b * QN + q) * 12;
    float al = (float)a * 0.2f;
    float py = pc[0];
    float px = pc[6];
    #pragma unroll
    for (int i = 1; i < 6; i++) { py = py * al + pc[i]; px = px * al + pc[6 + i]; }
    py = 2.0f * py - 1.0f;
    px = 2.0f * px - 1.0f;
    float gy = py + (2.0f * (-4.0f + (float)(p / 7) * (7.0f / 6.0f))) * (1.0f / 64.0f);
    float gx = px + (2.0f * (-4.0f + (float)(p % 7) * (7.0f / 6.0f))) * (1.0f / 64.0f);
    // NOTE the reference swap: fx from grid_y, fy from grid_x
    float fx = (gy + 1.0f) * 0.5f * 63.0f;
    float fy = (gx + 1.0f) * 0.5f * 63.0f;
    float x0 = floorf(fx), y0 = floorf(fy);
    co_x0[tid] = x0; co_y0[tid] = y0;
    co_wx[tid] = fx - x0; co_wy[tid] = fy - y0;
  }
  // zero pad rows 49..63
  {
    unsigned int* z = (unsigned int*)(spb + WS2 * SPB_LD);
    for (int i = tid; i < 15 * SPB_LD / 2; i += 256) z[i] = 0u;
  }
  __syncthreads();

  // Phase B: bilinear sampling, thread = channel, depth-1 software pipeline
  const float* xb = xT + (size_t)b * (4096 * CC);
  float n00, n01, n10, n11, wxn, wyn;
  {
    float x0 = co_x0[0], y0 = co_y0[0];
    wxn = co_wx[0]; wyn = co_wy[0];
    float x1 = x0 + 1.0f, y1 = y0 + 1.0f;
    int xi0 = (int)fminf(fmaxf(x0, 0.0f), 63.0f);
    int yi0 = (int)fminf(fmaxf(y0, 0.0f), 63.0f);
    int xi1 = (int)fminf(fmaxf(x1, 0.0f), 63.0f);
    int yi1 = (int)fminf(fmaxf(y1, 0.0f), 63.0f);
    bool vx0 = (x0 >= 0.0f) && (x0 <= 63.0f);
    bool vx1 = (x1 >= 0.0f) && (x1 <= 63.0f);
    bool vy0 = (y0 >= 0.0f) && (y0 <= 63.0f);
    bool vy1 = (y1 >= 0.0f) && (y1 <= 63.0f);
    n00 = (vx0 && vy0) ? xb[(yi0 * 64 + xi0) * CC + tid] : 0.0f;
    n01 = (vx1 && vy0) ? xb[(yi0 * 64 + xi1) * CC + tid] : 0.0f;
    n10 = (vx0 && vy1) ? xb[(yi1 * 64 + xi0) * CC + tid] : 0.0f;
    n11 = (vx1 && vy1) ? xb[(yi1 * 64 + xi1) * CC + tid] : 0.0f;
  }
  for (int r = 0; r < WS2; r++) {
    float c00 = n00, c01 = n01, c10 = n10, c11 = n11;
    float wx = wxn, wy = wyn;
    if (r + 1 < WS2) {
      int rn = r + 1;
      float x0 = co_x0[rn], y0 = co_y0[rn];
      wxn = co_wx[rn]; wyn = co_wy[rn];
      float x1 = x0 + 1.0f, y1 = y0 + 1.0f;
      int xi0 = (int)fminf(fmaxf(x0, 0.0f), 63.0f);
      int yi0 = (int)fminf(fmaxf(y0, 0.0f), 63.0f);
      int xi1 = (int)fminf(fmaxf(x1, 0.0f), 63.0f);
      int yi1 = (int)fminf(fmaxf(y1, 0.0f), 63.0f);
      bool vx0 = (x0 >= 0.0f) && (x0 <= 63.0f);
      bool vx1 = (x1 >= 0.0f) && (x1 <= 63.0f);
      bool vy0 = (y0 >= 0.0f) && (y0 <= 63.0f);
      bool vy1 = (y1 >= 0.0f) && (y1 <= 63.0f);
      n00 = (vx0 && vy0) ? xb[(yi0 * 64 + xi0) * CC + tid] : 0.0f;
      n01 = (vx1 && vy0) ? xb[(yi0 * 64 + xi1) * CC + tid] : 0.0f;
      n10 = (vx0 && vy1) ? xb[(yi1 * 64 + xi0) * CC + tid] : 0.0f;
      n11 = (vx1 && vy1) ? xb[(yi1 * 64 + xi1) * CC + tid] : 0.0f;
    }
    float s = c00 * (1.0f - wy) * (1.0f - wx) + c01 * (1.0f - wy) * wx
            + c10 * wy * (1.0f - wx) + c11 * wy * wx;
    spb[r * SPB_LD + tid] = f2bf(s);
  }
  __syncthreads();

  // Phase C: MFMA GEMM. Wave wv owns N-tiles [wv*12,+12) in 3 chunks of 4.
  const int lane = tid & 63;
  const int wv = tid >> 6;
  const int lm = lane & 15;
  const int lg = lane >> 4;
  unsigned short* qd = qkv_ws + (size_t)(b * NWIN + m) * QKV_SHORTS_PER_WIN;
  unsigned short* Cw = &Cwbuf[wv][0];

  for (int jc = 0; jc < 3; jc++) {
    const int nt0 = wv * 12 + jc * 4;
    const int ncol0 = nt0 * 16 + lm;
    f32x4 acc[4][4];
    #pragma unroll
    for (int j4 = 0; j4 < 4; j4++) {
      float bias = b_qkv[ncol0 + j4 * 16];
      #pragma unroll
      for (int mt = 0; mt < 4; mt++) acc[mt][j4] = (f32x4){bias, bias, bias, bias};
    }
    // register double-buffer for B fragments
    bf16x8 bnx[4];
    #pragma unroll
    for (int j4 = 0; j4 < 4; j4++)
      bnx[j4] = *(const bf16x8*)(wbp + (size_t)(((nt0 + j4) * 8 + 0) * 64 + lane) * 8);
    #pragma unroll
    for (int ks = 0; ks < 8; ks++) {
      bf16x8 bc[4];
      #pragma unroll
      for (int j4 = 0; j4 < 4; j4++) bc[j4] = bnx[j4];
      if (ks < 7) {
        #pragma unroll
        for (int j4 = 0; j4 < 4; j4++)
          bnx[j4] = *(const bf16x8*)(wbp + (size_t)(((nt0 + j4) * 8 + ks + 1) * 64 + lane) * 8);
      }
      bf16x8 af[4];
      #pragma unroll
      for (int mt = 0; mt < 4; mt++)
        af[mt] = *(const bf16x8*)(spb + (mt * 16 + lm) * SPB_LD + ks * 32 + lg * 8);
      #pragma unroll
      for (int j4 = 0; j4 < 4; j4++)
        #pragma unroll
        for (int mt = 0; mt < 4; mt++)
          acc[mt][j4] = __builtin_amdgcn_mfma_f32_16x16x32_bf16(af[mt], bc[j4], acc[mt][j4], 0, 0, 0);
    }
    // per-mt 16-row assembly + full-line stores (8 lines per uint4 instr)
    const int cbase = nt0 * 16;
    #pragma unroll
    for (int mt = 0; mt < 4; mt++) {
      #pragma unroll
      for (int reg = 0; reg < 4; reg++) {
        int rr = lg * 4 + reg;   // row within tile
        #pragma unroll
        for (int j4 = 0; j4 < 4; j4++)
          Cw[rr * CW_LD + j4 * 16 + lm] = f2bf(acc[mt][j4][reg]);
      }
      int r0 = mt * 16;
      #pragma unroll
      for (int half = 0; half < 2; half++) {
        int idx = half * 64 + lane;
        int r16 = idx >> 3;       // 0..15
        int seg = idx & 7;
        int r = r0 + r16;
        if (r < WS2)
          *(uint4*)(qd + (size_t)r * 768 + cbase + seg * 8) =
              *(const uint4*)(Cw + r16 * CW_LD + seg * 8);
      }
    }
  }
}

// ---------- K2: MFMA windowed attention, wave-per-head (2 heads/wave) ----------
// Round-11: O stores were 64B half-lines (r8 partial-line law, measured +75MB
// write +40MB fetch in r10's fused variant). Fix: assemble O rows (fp32,
// stride 36 floats = 144B, 16B-aligned, 2-way-max banks) in the dead P region
// after PV, then uint4 stores where 8 lanes = one complete 128B line.
#define P_LD 72    // P row stride in shorts
#define V_LD 72    // Vt row stride in shorts
#define OW_LD 36   // O assembly row stride in floats
#define P_WAVE (WS2 * P_LD)          // 3528 shorts per wave (7056 B >= 49*36*4=7056-16 OK)
#define V_OFF  (4 * P_WAVE)          // 14112 shorts
#define V_WAVE (32 * V_LD)           // 2304 shorts per wave
__launch_bounds__(256, 3)
__global__ void k2_attn(const unsigned short* __restrict__ qkv_ws,
                        float* __restrict__ o_ws) {
  __shared__ __align__(16) unsigned short lds[V_OFF + 4 * V_WAVE];  // 46656 B
  const int tid = threadIdx.x;
  const int lane = tid & 63;
  const int wv = tid >> 6;
  const int lm = lane & 15;
  const int lg = lane >> 4;
  const int m = blockIdx.x;
  const int b = blockIdx.y;
  const unsigned short* wsrc = qkv_ws + (size_t)(b * NWIN + m) * QKV_SHORTS_PER_WIN;
  const float scale = 0.17677669529663687f;  // 1/sqrt(32)
  unsigned short* P  = lds + wv * P_WAVE;
  unsigned short* Vt = lds + V_OFF + wv * V_WAVE;
  float* Ow = (float*)P;   // O assembly reuses P region after PV (same-wave ds order)

  for (int hh = 0; hh < 2; hh++) {
    const int h = wv * 2 + hh;

    // Stage V^T into LDS: Vt[d][r], rows 49..63 zeroed
    {
      int dd = lane & 31;
      int rb = lane >> 5;
      #pragma unroll
      for (int i = 0; i < 32; i++) {
        int rr = i * 2 + rb;
        unsigned short val = 0;
        if (rr < WS2) val = wsrc[(size_t)rr * 768 + 512 + h * HDD + dd];
        Vt[dd * V_LD + rr] = val;
      }
    }

    // Q/K fragments straight from global [r][j], row-clamped
    bf16x8 qf[4], kf[4];
    #pragma unroll
    for (int t = 0; t < 4; t++) {
      int r = t * 16 + lm; if (r > 48) r = 48;
      qf[t] = *(const bf16x8*)(wsrc + (size_t)r * 768 + h * HDD + lg * 8);
      kf[t] = *(const bf16x8*)(wsrc + (size_t)r * 768 + 256 + h * HDD + lg * 8);
    }

    // S = Q K^T
    f32x4 s[4][4];
    #pragma unroll
    for (int mt = 0; mt < 4; mt++)
      #pragma unroll
      for (int nt = 0; nt < 4; nt++) {
        s[mt][nt] = (f32x4){0.f, 0.f, 0.f, 0.f};
        s[mt][nt] = __builtin_amdgcn_mfma_f32_16x16x32_bf16(qf[mt], kf[nt], s[mt][nt], 0, 0, 0);
      }

    #pragma unroll
    for (int mt = 0; mt < 4; mt++)
      #pragma unroll
      for (int nt = 0; nt < 4; nt++) {
        bool badcol = (nt == 3) && (lm > 0);
        #pragma unroll
        for (int reg = 0; reg < 4; reg++)
          s[mt][nt][reg] = badcol ? -1e30f : s[mt][nt][reg] * scale;
      }

    // softmax over keys (pos_bias is per-row constant: cancels exactly)
    #pragma unroll
    for (int mt = 0; mt < 4; mt++) {
      #pragma unroll
      for (int reg = 0; reg < 4; reg++) {
        float mx = fmaxf(fmaxf(s[mt][0][reg], s[mt][1][reg]),
                         fmaxf(s[mt][2][reg], s[mt][3][reg]));
        #pragma unroll
        for (int off = 1; off < 16; off <<= 1) mx = fmaxf(mx, __shfl_xor(mx, off));
        float sum = 0.0f;
        #pragma unroll
        for (int nt = 0; nt < 4; nt++) {
          float e = __expf(s[mt][nt][reg] - mx);
          s[mt][nt][reg] = e;
          sum += e;
        }
        #pragma unroll
        for (int off = 1; off < 16; off <<= 1) sum += __shfl_xor(sum, off);
        float inv = 1.0f / sum;
        #pragma unroll
        for (int nt = 0; nt < 4; nt++) s[mt][nt][reg] *= inv;
      }
    }

    // P (bf16) -> LDS row-major [p][r2], rows >=49 suppressed (region is 49 rows)
    #pragma unroll
    for (int mt = 0; mt < 4; mt++)
      #pragma unroll
      for (int nt = 0; nt < 4; nt++)
        #pragma unroll
        for (int reg = 0; reg < 4; reg++) {
          int p = mt * 16 + lg * 4 + reg;
          if (p < WS2) P[p * P_LD + nt * 16 + lm] = f2bf(s[mt][nt][reg]);
        }

    // O = P V
    f32x4 o[4][2];
    #pragma unroll
    for (int mt = 0; mt < 4; mt++)
      #pragma unroll
      for (int nt2 = 0; nt2 < 2; nt2++) o[mt][nt2] = (f32x4){0.f, 0.f, 0.f, 0.f};
    #pragma unroll
    for (int ks = 0; ks < 2; ks++) {
      bf16x8 vf[2];
      #pragma unroll
      for (int nt2 = 0; nt2 < 2; nt2++)
        vf[nt2] = *(const bf16x8*)(Vt + (nt2 * 16 + lm) * V_LD + ks * 32 + lg * 8);
      #pragma unroll
      for (int mt = 0; mt < 4; mt++) {
        bf16x8 af = *(const bf16x8*)(P + (mt * 16 + lm) * P_LD + ks * 32 + lg * 8);
        #pragma unroll
        for (int nt2 = 0; nt2 < 2; nt2++)
          o[mt][nt2] = __builtin_amdgcn_mfma_f32_16x16x32_bf16(af, vf[nt2], o[mt][nt2], 0, 0, 0);
      }
    }

    // O -> LDS assembly (P region dead after PV; same-wave ds ops are in
    // program order, so these writes can't pass the P reads above)
    #pragma unroll
    for (int mt = 0; mt < 4; mt++)
      #pragma unroll
      for (int reg = 0; reg < 4; reg++) {
        int p = mt * 16 + lg * 4 + reg;
        if (p < WS2) {
          #pragma unroll
          for (int nt2 = 0; nt2 < 2; nt2++)
            Ow[p * OW_LD + nt2 * 16 + lm] = o[mt][nt2][reg];
        }
      }
    // full-line stores: 8 lanes x uint4 = one complete 128B line per row
    // (row base = ob + p*19200 floats; 76800B stride, 128B-aligned)
    float* ob = o_ws + (size_t)b * O_PER_B + ((size_t)h * WS2 * NWIN + m) * HDD;
    for (int idx = lane; idx < WS2 * 8; idx += 64) {
      int p = idx >> 3, seg = idx & 7;
      *(uint4*)(ob + (size_t)p * (NWIN * HDD) + seg * 4) =
          *(const uint4*)(Ow + p * OW_LD + seg * 4);
    }
  }
}

// ---------- K3: conv (49-tap over p') + projection ----------
__global__ void k3_conv_proj(const float* __restrict__ o_ws,
                             const float* __restrict__ conv_w,
                             const float* __restrict__ conv_b,
                             const float* __restrict__ w_proj,
                             const float* __restrict__ b_proj,
                             float* __restrict__ out) {
  __shared__ float yv[CC];
  __shared__ float cw[WS2];
  const int tid = threadIdx.x;
  const int np = blockIdx.x;
  const int b = blockIdx.y;
  if (tid < WS2) cw[tid] = conv_w[tid];
  __syncthreads();
  const float* base = o_ws + (size_t)b * O_PER_B + (size_t)np * (WS2 * CC);
  float acc = conv_b[0];
  for (int p = 0; p < WS2; p++)
    acc += cw[p] * base[p * CC + tid];
  yv[tid] = acc;
  __syncthreads();
  const float4* y4 = (const float4*)yv;
  const float4* w4 = (const float4*)(w_proj + (size_t)tid * CC);
  float s = b_proj[tid];
  float s2 = 0.0f;
  #pragma unroll 8
  for (int c4 = 0; c4 < 64; c4++) {
    float4 a = y4[c4], wv2 = w4[c4];
    s2 += a.x * wv2.x + a.y * wv2.y + a.z * wv2.z + a.w * wv2.w;
  }
  out[((size_t)(b * NWIN + np)) * CC + tid] = s + s2;
}

extern "C" void kernel_launch(void* const* d_in, const int* in_sizes, int n_in,
                              void* d_out, int out_size, void* d_ws, size_t ws_size,
                              hipStream_t stream) {
  const float* x        = (const float*)d_in[0];
  const float* polys    = (const float*)d_in[1];
  const float* w_qkv    = (const float*)d_in[2];
  const float* b_qkv    = (const float*)d_in[3];
  const float* w_proj   = (const float*)d_in[4];
  const float* b_proj   = (const float*)d_in[5];
  const float* conv_w   = (const float*)d_in[6];
  const float* conv_b   = (const float*)d_in[7];
  float* out = (float*)d_out;

  char* ws = (char*)d_ws;
  float* xT = (float*)ws;
  unsigned short* wbp = (unsigned short*)(ws + XT_BYTES);
  unsigned short* qkv_ws = (unsigned short*)(ws + XT_BYTES + WB_BYTES);
  float* o_ws = (float*)(ws + XT_BYTES + WB_BYTES + QKV_BYTES);

  hipLaunchKernelGGL(k0_transpose, dim3(128, 8, 2), dim3(32, 8), 0, stream, x, xT);
  hipLaunchKernelGGL(k05_wpack, dim3(96), dim3(256), 0, stream, w_qkv, wbp);
  hipLaunchKernelGGL(k1_sample_qkv, dim3(NWIN, B_), dim3(256), 0, stream,
                     xT, polys, wbp, b_qkv, qkv_ws);
  hipLaunchKernelGGL(k2_attn, dim3(NWIN, B_), dim3(256), 0, stream,
                     qkv_ws, o_ws);
  hipLaunchKernelGGL(k3_conv_proj, dim3(NWIN, B_), dim3(256), 0, stream,
                     o_ws, conv_w, conv_b, w_proj, b_proj, out);
}